// Round 12
// baseline (1388.946 us; speedup 1.0000x reference)
//
#include <hip/hip_runtime.h>
#include <stdint.h>

typedef unsigned short u16;
typedef unsigned int u32;
typedef _Float16 f16;
typedef __attribute__((ext_vector_type(2))) __fp16 h16x2;
typedef __attribute__((ext_vector_type(8))) _Float16 f16x8;
typedef __attribute__((ext_vector_type(4))) float f32x4;
typedef __attribute__((ext_vector_type(4))) unsigned short u16x4;
typedef __attribute__((ext_vector_type(4))) unsigned int u32x4;

#define T_SEQ  256
#define BATCH  32
#define DIM    768
#define HID    768
#define G3     2304
#define N_ALL  4608
#define NSLICE 48
#define NBLK   96
#define FLAG_STRIDE 32   // ints; 128B per flag slot

__device__ __forceinline__ u16 f2h(float f) {
  return __builtin_bit_cast(u16, (f16)f);
}
__device__ __forceinline__ float h2f(u16 h) {
  return (float)__builtin_bit_cast(f16, h);
}

// L2-bypass (coherent at memory-side cache) ops; sc0 sc1 on both sides, no fences.
__device__ __forceinline__ f16x8 load_coh16(const u16* p) {
  f16x8 v;
  asm volatile("global_load_dwordx4 %0, %1, off sc0 sc1" : "=v"(v) : "v"(p));
  return v;
}
__device__ __forceinline__ void store_coh16(u16* p, f16x8 v) {
  asm volatile("global_store_dwordx4 %0, %1, off sc0 sc1" :: "v"(p), "v"(v));
}
__device__ __forceinline__ void wait_vm0() {
  asm volatile("s_waitcnt vmcnt(0)" ::: "memory");
}
__device__ __forceinline__ u32 pkrtz(float a, float b) {
  h16x2 p = __builtin_amdgcn_cvt_pkrtz(a, b);
  return __builtin_bit_cast(u32, p);
}
__device__ __forceinline__ f16x8 cvt8(float4 a, float4 b) {
  u32x4 r;
  r.x = pkrtz(a.x, a.y);
  r.y = pkrtz(a.z, a.w);
  r.z = pkrtz(b.x, b.y);
  r.w = pkrtz(b.z, b.w);
  return __builtin_bit_cast(f16x8, r);
}

// ---------- f32 -> f16 convert (for Whh only) ----------
__global__ void k_cvt(const float* __restrict__ in, u16* __restrict__ out, int n4) {
  int i = blockIdx.x * blockDim.x + threadIdx.x;
  if (i >= n4) return;
  float4 v = ((const float4*)in)[i];
  u16x4 o;
  o[0] = f2h(v.x); o[1] = f2h(v.y); o[2] = f2h(v.z); o[3] = f2h(v.w);
  ((u16x4*)out)[i] = o;
}

// ---------- gx = X*Wih^T + bih, f32 inputs converted inline, f16 out ----------
__global__ __launch_bounds__(256) void k_gemm(
    const float* __restrict__ X, const float* __restrict__ Wf,
    const float* __restrict__ Wb,
    const float* __restrict__ bihf, const float* __restrict__ bihb,
    u16* __restrict__ gx)
{
  __shared__ __align__(16) u16 As[128 * 32];
  __shared__ __align__(16) u16 Bs[128 * 32];
  const int tid  = threadIdx.x;
  const int lane = tid & 63, wave = tid >> 6;
  const int wm = wave >> 1, wn = wave & 1;
  const int m0 = blockIdx.y * 128;
  const int n0 = blockIdx.x * 128;
  const int lr = lane & 15, lk = lane >> 4;
  f32x4 acc[4][4] = {};
  for (int k0 = 0; k0 < DIM; k0 += 32) {
    __syncthreads();
    #pragma unroll
    for (int i = 0; i < 2; ++i) {
      int cidx = i * 256 + tid;
      int row = cidx >> 2, kk = (cidx & 3) * 8;
      const float* ap = &X[(size_t)(m0 + row) * DIM + k0 + kk];
      *(f16x8*)&As[cidx * 8] = cvt8(*(const float4*)ap, *(const float4*)(ap + 4));
      int n = n0 + row;
      const float* bp = (n < G3 ? &Wf[(size_t)n * DIM] : &Wb[(size_t)(n - G3) * DIM]) + k0 + kk;
      *(f16x8*)&Bs[cidx * 8] = cvt8(*(const float4*)bp, *(const float4*)(bp + 4));
    }
    __syncthreads();
    f16x8 af[4], bfr[4];
    #pragma unroll
    for (int f = 0; f < 4; ++f) {
      af[f]  = *(const f16x8*)&As[(wm * 64 + f * 16 + lr) * 32 + lk * 8];
      bfr[f] = *(const f16x8*)&Bs[(wn * 64 + f * 16 + lr) * 32 + lk * 8];
    }
    #pragma unroll
    for (int fm = 0; fm < 4; ++fm)
      #pragma unroll
      for (int fn = 0; fn < 4; ++fn)
        acc[fm][fn] = __builtin_amdgcn_mfma_f32_16x16x32_f16(af[fm], bfr[fn], acc[fm][fn], 0, 0, 0);
  }
  #pragma unroll
  for (int fm = 0; fm < 4; ++fm)
    #pragma unroll
    for (int fn = 0; fn < 4; ++fn) {
      int n = n0 + wn * 64 + fn * 16 + lr;
      float bias = (n < G3) ? bihf[n] : bihb[n - G3];
      #pragma unroll
      for (int r = 0; r < 4; ++r) {
        int m = m0 + wm * 64 + fm * 16 + lk * 4 + r;
        gx[(size_t)m * N_ALL + n] = f2h(acc[fm][fn][r] + bias);
      }
    }
}

// ---------- persistent bidirectional GRU scan: DMA-wave specialization ----------
// 96 blocks: dir = blk/48, slice of 16 hidden cols = blk%48.
// Waves 0-2: K split 3x256 (8 ks-slices each). Wave0 additionally: epilogue,
// publish 1KB, vm0, flag. Wave3: pure DMA+poll wave — issues next-step gx loads
// and prev-step out stores at step start (drain overlaps MFMA+epilogue), writes
// gxl after mid barrier, polls the 48 own-dir flags between mid and end barriers.
// Wave0 never touches HBM: its vmem ops are only L3 (ah loads, publish, flag).
__global__ __launch_bounds__(256, 1) void k_gru(
    const u16* __restrict__ whh,   // [4608][768] f16
    const u16* __restrict__ gx,    // [8192][4608] f16 (includes bih)
    const float* __restrict__ h0,
    const float* __restrict__ bhhf, const float* __restrict__ bhhb,
    const int* __restrict__ lengths,
    u16* __restrict__ hbuf,        // f16 [2 par][2 dir][32][768]
    float* __restrict__ out, int* __restrict__ flags)
{
  const int blk   = blockIdx.x;
  const int dir   = blk / NSLICE;
  const int slice = blk % NSLICE;
  const int hbase = slice * 16;
  const int tid = threadIdx.x, lane = tid & 63, wave = tid >> 6;
  const int lr = lane & 15, lk = lane >> 4;
  const int c = hbase + lr;
  const int cc = lane & 15, bq = lane >> 4;   // wave3 DMA layout: 16 cols x 4 row-octs

  __shared__ __align__(16) float part[2][2][3][64][4];  // 12288 B (waves 1,2)
  __shared__ __align__(16) u16 gxl[2][3][32][16];       //  6144 B
  __shared__ __align__(16) float outb[2][32][16];       //  4096 B
  __shared__ __align__(16) u16 hx[32][16];              //  1024 B

  // Whh B-fragments (waves 0-2 only), register-resident for the whole scan.
  f16x8 bw[3][8];
  if (wave < 3) {
    #pragma unroll
    for (int g = 0; g < 3; ++g)
      #pragma unroll
      for (int ks = 0; ks < 8; ++ks)
        bw[g][ks] = *(const f16x8*)&whh[(size_t)(dir * G3 + g * HID + hbase + lr) * HID
                                        + wave * 256 + ks * 32 + lk * 8];
  }

  float hst[2][4];
  float bh[3] = {0.f, 0.f, 0.f};
  int lenv[2][4];
  if (wave == 0) {
    const float* bhp = dir ? bhhb : bhhf;
    #pragma unroll
    for (int g = 0; g < 3; ++g) bh[g] = bhp[g * HID + c];
    #pragma unroll
    for (int m = 0; m < 2; ++m)
      #pragma unroll
      for (int r = 0; r < 4; ++r) {
        int b = m * 16 + lk * 4 + r;
        float h = h0[(size_t)dir * BATCH * HID + (size_t)b * HID + c];
        hst[m][r] = h;
        lenv[m][r] = lengths[b];
        hx[b][lr] = f2h(h);
      }
    asm volatile("s_waitcnt lgkmcnt(0)" ::: "memory");
    {
      f16x8 hv = *(const f16x8*)&hx[lane >> 1][(lane & 1) * 8];
      store_coh16(&hbuf[(size_t)(dir * BATCH + (lane >> 1)) * HID + hbase + (lane & 1) * 8], hv);
    }
    wait_vm0();
    if (lane == 0)
      __hip_atomic_store(&flags[blk * FLAG_STRIDE], 1, __ATOMIC_RELAXED, __HIP_MEMORY_SCOPE_AGENT);
  } else if (wave == 3) {
    // preload gxl[0] for t(0)
    int t0 = dir ? (T_SEQ - 1) : 0;
    #pragma unroll
    for (int g = 0; g < 3; ++g)
      #pragma unroll
      for (int j = 0; j < 8; ++j) {
        int b = bq * 8 + j;
        gxl[0][g][b][cc] = gx[((size_t)t0 * BATCH + b) * N_ALL + dir * G3 + g * HID + hbase + cc];
      }
    if (lane < NSLICE) {
      const int watch = (dir * NSLICE + lane) * FLAG_STRIDE;
      while (__hip_atomic_load(&flags[watch], __ATOMIC_RELAXED, __HIP_MEMORY_SCOPE_AGENT) < 1)
        __builtin_amdgcn_s_sleep(1);
    }
  }
  __syncthreads();

  for (int s = 0; s < T_SEQ; ++s) {
    const int par = s & 1;
    const int t = dir ? (T_SEQ - 1 - s) : s;
    f32x4 acc[2][3] = {};
    u16 gpre[24];
    if (wave < 3) {
      const u16* hb = hbuf + (size_t)(par * 2 + dir) * BATCH * HID;
      f16x8 ah[2][8];
      #pragma unroll
      for (int m2 = 0; m2 < 2; ++m2)
        #pragma unroll
        for (int ks = 0; ks < 8; ++ks)
          ah[m2][ks] = load_coh16(&hb[(size_t)(m2 * 16 + lr) * HID + wave * 256 + ks * 32 + lk * 8]);
      wait_vm0();
      __builtin_amdgcn_sched_barrier(0);
      #pragma unroll
      for (int ks = 0; ks < 8; ++ks)
        #pragma unroll
        for (int m2 = 0; m2 < 2; ++m2)
          #pragma unroll
          for (int g = 0; g < 3; ++g)
            acc[m2][g] = __builtin_amdgcn_mfma_f32_16x16x32_f16(ah[m2][ks], bw[g][ks], acc[m2][g], 0, 0, 0);
      if (wave != 0) {
        #pragma unroll
        for (int m2 = 0; m2 < 2; ++m2)
          #pragma unroll
          for (int g = 0; g < 3; ++g)
            *(f32x4*)&part[wave - 1][m2][g][lane][0] = acc[m2][g];
      }
    } else {
      // wave3 DMA: issue next-step gx loads; store prev-step out rows
      if (s + 1 < T_SEQ) {
        int t2 = dir ? (T_SEQ - 2 - s) : (s + 1);
        #pragma unroll
        for (int g = 0; g < 3; ++g)
          #pragma unroll
          for (int j = 0; j < 8; ++j)
            gpre[g * 8 + j] = gx[((size_t)t2 * BATCH + bq * 8 + j) * N_ALL
                                 + dir * G3 + g * HID + hbase + cc];
      }
      if (s > 0) {
        int tprev = dir ? (T_SEQ - s) : (s - 1);
        #pragma unroll
        for (int j = 0; j < 8; ++j) {
          float v = outb[par ^ 1][bq * 8 + j][cc];
          __builtin_nontemporal_store(v,
              &out[((size_t)tprev * BATCH + bq * 8 + j) * (2 * HID) + (size_t)dir * HID + hbase + cc]);
        }
      }
    }
    __syncthreads();                       // mid barrier
    if (wave == 0) {
      u16* hbn = hbuf + (size_t)((par ^ 1) * 2 + dir) * BATCH * HID;
      #pragma unroll
      for (int m = 0; m < 2; ++m) {
        f32x4 gh[3];
        #pragma unroll
        for (int g = 0; g < 3; ++g) {
          f32x4 v = acc[m][g];
          #pragma unroll
          for (int w = 0; w < 2; ++w) v += *(const f32x4*)&part[w][m][g][lane][0];
          gh[g] = v;
        }
        #pragma unroll
        for (int r = 0; r < 4; ++r) {
          int b = m * 16 + lk * 4 + r;
          float xr = h2f(gxl[par][0][b][lr]);
          float xz = h2f(gxl[par][1][b][lr]);
          float xn = h2f(gxl[par][2][b][lr]);
          float rg = 1.f / (1.f + __expf(-(xr + gh[0][r] + bh[0])));
          float zg = 1.f / (1.f + __expf(-(xz + gh[1][r] + bh[1])));
          float e2 = __expf(2.f * (xn + rg * (gh[2][r] + bh[2])));
          float ng = 1.f - 2.f / (e2 + 1.f);
          float hp = hst[m][r];
          bool msk = t < lenv[m][r];
          float hn = msk ? ((1.f - zg) * ng + zg * hp) : hp;
          hst[m][r] = hn;
          outb[par][b][lr] = msk ? hn : 0.f;
          hx[b][lr] = f2h(hn);
        }
      }
      // transposed coherent publish of h_{s+1}, ack, flag — all L3, no HBM
      asm volatile("s_waitcnt lgkmcnt(0)" ::: "memory");
      {
        f16x8 hv = *(const f16x8*)&hx[lane >> 1][(lane & 1) * 8];
        store_coh16(&hbn[(size_t)(lane >> 1) * HID + hbase + (lane & 1) * 8], hv);
      }
      wait_vm0();
      if (lane == 0)
        __hip_atomic_store(&flags[blk * FLAG_STRIDE], s + 2, __ATOMIC_RELAXED, __HIP_MEMORY_SCOPE_AGENT);
    } else if (wave == 3) {
      // land gx into gxl (vm waits inserted by reg deps), then poll
      if (s + 1 < T_SEQ) {
        #pragma unroll
        for (int g = 0; g < 3; ++g)
          #pragma unroll
          for (int j = 0; j < 8; ++j)
            gxl[par ^ 1][g][bq * 8 + j][cc] = gpre[g * 8 + j];
      }
      if (lane < NSLICE) {
        const int watch = (dir * NSLICE + lane) * FLAG_STRIDE;
        while (__hip_atomic_load(&flags[watch], __ATOMIC_RELAXED, __HIP_MEMORY_SCOPE_AGENT) < s + 2)
          __builtin_amdgcn_s_sleep(1);
      }
    }
    __syncthreads();                       // end barrier
  }
  if (wave == 0) {
    #pragma unroll
    for (int m = 0; m < 2; ++m)
      #pragma unroll
      for (int r = 0; r < 4; ++r) {
        int b = m * 16 + lk * 4 + r;
        out[(size_t)T_SEQ * BATCH * 2 * HID + (size_t)dir * BATCH * HID + (size_t)b * HID + c] = hst[m][r];
      }
  } else if (wave == 3) {
    // flush the final step's out rows
    int tlast = dir ? 0 : (T_SEQ - 1);
    #pragma unroll
    for (int j = 0; j < 8; ++j) {
      float v = outb[(T_SEQ - 1) & 1][bq * 8 + j][cc];
      __builtin_nontemporal_store(v,
          &out[((size_t)tlast * BATCH + bq * 8 + j) * (2 * HID) + (size_t)dir * HID + hbase + cc]);
    }
  }
}

extern "C" void kernel_launch(void* const* d_in, const int* in_sizes, int n_in,
                              void* d_out, int out_size, void* d_ws, size_t ws_size,
                              hipStream_t stream) {
  const float* x     = (const float*)d_in[0];
  const float* h0    = (const float*)d_in[1];
  const float* wihf  = (const float*)d_in[2];
  const float* whhf  = (const float*)d_in[3];
  const float* bihf  = (const float*)d_in[4];
  const float* bhhf  = (const float*)d_in[5];
  const float* wihb  = (const float*)d_in[6];
  const float* whhb  = (const float*)d_in[7];
  const float* bihb  = (const float*)d_in[8];
  const float* bhhb  = (const float*)d_in[9];
  const int* lengths = (const int*)d_in[10];
  float* out = (float*)d_out;
  char* ws = (char*)d_ws;

  int* flags = (int*)(ws + 0);            //     12,288 B (96 slots x 128B)
  u16* whh_h = (u16*)(ws + 24576);        //  7,077,888 B
  u16* hbuf  = (u16*)(ws + 7102464);      //    196,608 B
  u16* gx    = (u16*)(ws + 7299072);      // 75,497,472 B

  k_cvt<<<1728, 256, 0, stream>>>(whhf, whh_h,            442368);
  k_cvt<<<1728, 256, 0, stream>>>(whhb, whh_h + 1769472,  442368);
  (void)hipMemsetAsync(flags, 0, NBLK * FLAG_STRIDE * sizeof(int), stream);
  k_gemm<<<dim3(36, 64), 256, 0, stream>>>(x, wihf, wihb, bihf, bihb, gx);
  k_gru<<<NBLK, 256, 0, stream>>>(whh_h, gx, h0, bhhf, bhhb, lengths, hbuf, out, flags);
}

// Round 13
// 1220.166 us; speedup vs baseline: 1.1383x; 1.1383x over previous
//
#include <hip/hip_runtime.h>
#include <stdint.h>

typedef unsigned short u16;
typedef unsigned int u32;
typedef _Float16 f16;
typedef __attribute__((ext_vector_type(2))) __fp16 h16x2;
typedef __attribute__((ext_vector_type(8))) _Float16 f16x8;
typedef __attribute__((ext_vector_type(4))) float f32x4;
typedef __attribute__((ext_vector_type(4))) unsigned short u16x4;
typedef __attribute__((ext_vector_type(4))) unsigned int u32x4;

#define T_SEQ  256
#define BATCH  32
#define DIM    768
#define HID    768
#define G3     2304
#define N_ALL  4608
#define NSLICE 48
#define NBLK   96
#define FLAG_STRIDE 32   // ints; 128B per flag slot

__device__ __forceinline__ u16 f2h(float f) {
  return __builtin_bit_cast(u16, (f16)f);
}
__device__ __forceinline__ float h2f(u16 h) {
  return (float)__builtin_bit_cast(f16, h);
}

// L2-bypass (coherent at memory-side cache) ops; sc0 sc1 on both sides, no fences.
__device__ __forceinline__ f16x8 load_coh16(const u16* p) {
  f16x8 v;
  asm volatile("global_load_dwordx4 %0, %1, off sc0 sc1" : "=v"(v) : "v"(p));
  return v;
}
__device__ __forceinline__ void store_coh16(u16* p, f16x8 v) {
  asm volatile("global_store_dwordx4 %0, %1, off sc0 sc1" :: "v"(p), "v"(v));
}
__device__ __forceinline__ void wait_vm0() {
  asm volatile("s_waitcnt vmcnt(0)" ::: "memory");
}
__device__ __forceinline__ u32 pkrtz(float a, float b) {
  h16x2 p = __builtin_amdgcn_cvt_pkrtz(a, b);
  return __builtin_bit_cast(u32, p);
}
__device__ __forceinline__ f16x8 cvt8(float4 a, float4 b) {
  u32x4 r;
  r.x = pkrtz(a.x, a.y);
  r.y = pkrtz(a.z, a.w);
  r.z = pkrtz(b.x, b.y);
  r.w = pkrtz(b.z, b.w);
  return __builtin_bit_cast(f16x8, r);
}

// ---------- f32 -> f16 convert (for Whh only) ----------
__global__ void k_cvt(const float* __restrict__ in, u16* __restrict__ out, int n4) {
  int i = blockIdx.x * blockDim.x + threadIdx.x;
  if (i >= n4) return;
  float4 v = ((const float4*)in)[i];
  u16x4 o;
  o[0] = f2h(v.x); o[1] = f2h(v.y); o[2] = f2h(v.z); o[3] = f2h(v.w);
  ((u16x4*)out)[i] = o;
}

// ---------- gx = X*Wih^T + bih, f32 inputs converted inline, f16 out ----------
__global__ __launch_bounds__(256) void k_gemm(
    const float* __restrict__ X, const float* __restrict__ Wf,
    const float* __restrict__ Wb,
    const float* __restrict__ bihf, const float* __restrict__ bihb,
    u16* __restrict__ gx)
{
  __shared__ __align__(16) u16 As[128 * 32];
  __shared__ __align__(16) u16 Bs[128 * 32];
  const int tid  = threadIdx.x;
  const int lane = tid & 63, wave = tid >> 6;
  const int wm = wave >> 1, wn = wave & 1;
  const int m0 = blockIdx.y * 128;
  const int n0 = blockIdx.x * 128;
  const int lr = lane & 15, lk = lane >> 4;
  f32x4 acc[4][4] = {};
  for (int k0 = 0; k0 < DIM; k0 += 32) {
    __syncthreads();
    #pragma unroll
    for (int i = 0; i < 2; ++i) {
      int cidx = i * 256 + tid;
      int row = cidx >> 2, kk = (cidx & 3) * 8;
      const float* ap = &X[(size_t)(m0 + row) * DIM + k0 + kk];
      *(f16x8*)&As[cidx * 8] = cvt8(*(const float4*)ap, *(const float4*)(ap + 4));
      int n = n0 + row;
      const float* bp = (n < G3 ? &Wf[(size_t)n * DIM] : &Wb[(size_t)(n - G3) * DIM]) + k0 + kk;
      *(f16x8*)&Bs[cidx * 8] = cvt8(*(const float4*)bp, *(const float4*)(bp + 4));
    }
    __syncthreads();
    f16x8 af[4], bfr[4];
    #pragma unroll
    for (int f = 0; f < 4; ++f) {
      af[f]  = *(const f16x8*)&As[(wm * 64 + f * 16 + lr) * 32 + lk * 8];
      bfr[f] = *(const f16x8*)&Bs[(wn * 64 + f * 16 + lr) * 32 + lk * 8];
    }
    #pragma unroll
    for (int fm = 0; fm < 4; ++fm)
      #pragma unroll
      for (int fn = 0; fn < 4; ++fn)
        acc[fm][fn] = __builtin_amdgcn_mfma_f32_16x16x32_f16(af[fm], bfr[fn], acc[fm][fn], 0, 0, 0);
  }
  #pragma unroll
  for (int fm = 0; fm < 4; ++fm)
    #pragma unroll
    for (int fn = 0; fn < 4; ++fn) {
      int n = n0 + wn * 64 + fn * 16 + lr;
      float bias = (n < G3) ? bihf[n] : bihb[n - G3];
      #pragma unroll
      for (int r = 0; r < 4; ++r) {
        int m = m0 + wm * 64 + fm * 16 + lk * 4 + r;
        gx[(size_t)m * N_ALL + n] = f2h(acc[fm][fn][r] + bias);
      }
    }
}

// ---------- persistent bidirectional GRU scan (windowed per-wave flag polls) ----------
// 96 blocks: dir = blk/48, slice of 16 hidden cols = blk%48. 4 waves split K=768
// (192 cols each). Each wave polls the 12 flags of exactly the slices covering
// its own K-window (lane<12, one flag per lane), then loads its ah chunks.
// One barrier per step (mid). Partials parity-double-buffered so waves 1-3 can
// pipeline into step s+1 while wave0 finishes step s's epilogue tail.
__global__ __launch_bounds__(256, 1) void k_gru(
    const u16* __restrict__ whh,   // [4608][768] f16
    const u16* __restrict__ gx,    // [8192][4608] f16 (includes bih)
    const float* __restrict__ h0,
    const float* __restrict__ bhhf, const float* __restrict__ bhhb,
    const int* __restrict__ lengths,
    u16* __restrict__ hbuf,        // f16 [2 par][2 dir][32][768]
    float* __restrict__ out, int* __restrict__ flags)
{
  const int blk   = blockIdx.x;
  const int dir   = blk / NSLICE;
  const int slice = blk % NSLICE;
  const int hbase = slice * 16;
  const int tid = threadIdx.x, lane = tid & 63, wave = tid >> 6;
  const int lr = lane & 15, lk = lane >> 4;
  const int c = hbase + lr;
  // this wave's flag window: slices wave*12 .. wave*12+11 cover cols [wave*192, wave*192+192)
  const int myflag = (lane < 12) ? (dir * NSLICE + wave * 12 + lane) * FLAG_STRIDE : 0;

  __shared__ __align__(16) float part[2][3][2][3][64][4];  // 36864 B, parity-doubled
  __shared__ __align__(16) u16 hx[32][16];                 //  1024 B

  // Whh B-fragments, register-resident for the whole scan.
  f16x8 bw[3][6];
  #pragma unroll
  for (int g = 0; g < 3; ++g)
    #pragma unroll
    for (int ks = 0; ks < 6; ++ks)
      bw[g][ks] = *(const f16x8*)&whh[(size_t)(dir * G3 + g * HID + hbase + lr) * HID
                                      + wave * 192 + ks * 32 + lk * 8];

  float hst[2][4];
  float bh[3] = {0.f, 0.f, 0.f};
  int lenv[2][4];
  u16 g0[2][4], g1[2][4], g2[2][4];
  if (wave == 0) {
    #pragma unroll
    for (int m = 0; m < 2; ++m)
      #pragma unroll
      for (int r = 0; r < 4; ++r) {
        int b = m * 16 + lk * 4 + r;
        float h = h0[(size_t)dir * BATCH * HID + (size_t)b * HID + c];
        hst[m][r] = h;
        lenv[m][r] = lengths[b];
        hx[b][lr] = f2h(h);
      }
    const float* bhp = dir ? bhhb : bhhf;
    #pragma unroll
    for (int g = 0; g < 3; ++g) bh[g] = bhp[g * HID + c];
    // transposed coherent publish of h0 (parity 0)
    asm volatile("s_waitcnt lgkmcnt(0)" ::: "memory");
    {
      f16x8 hv = *(const f16x8*)&hx[lane >> 1][(lane & 1) * 8];
      store_coh16(&hbuf[(size_t)(dir * BATCH + (lane >> 1)) * HID + hbase + (lane & 1) * 8], hv);
    }
    wait_vm0();
    if (lane == 0)
      __hip_atomic_store(&flags[blk * FLAG_STRIDE], 1, __ATOMIC_RELAXED, __HIP_MEMORY_SCOPE_AGENT);
    // prefetch gx for first step, then drain
    int t0 = dir ? (T_SEQ - 1) : 0;
    #pragma unroll
    for (int m = 0; m < 2; ++m)
      #pragma unroll
      for (int r = 0; r < 4; ++r) {
        int b = m * 16 + lk * 4 + r;
        size_t off = ((size_t)t0 * BATCH + b) * N_ALL + dir * G3 + c;
        g0[m][r] = gx[off]; g1[m][r] = gx[off + HID]; g2[m][r] = gx[off + 2 * HID];
      }
    wait_vm0();
  }
  __syncthreads();

  for (int s = 0; s < T_SEQ; ++s) {
    const int par = s & 1;
    const int t = dir ? (T_SEQ - 1 - s) : s;
    // ---- windowed flag poll: h^s ready when window flags >= s+1 ----
    if (lane < 12) {
      while (__hip_atomic_load(&flags[myflag], __ATOMIC_RELAXED, __HIP_MEMORY_SCOPE_AGENT) < s + 1)
        __builtin_amdgcn_s_sleep(1);
    }
    const u16* hb = hbuf + (size_t)(par * 2 + dir) * BATCH * HID;
    f16x8 ah[2][6];
    #pragma unroll
    for (int m = 0; m < 2; ++m)
      #pragma unroll
      for (int ks = 0; ks < 6; ++ks)
        ah[m][ks] = load_coh16(&hb[(size_t)(m * 16 + lr) * HID + wave * 192 + ks * 32 + lk * 8]);
    wait_vm0();
    __builtin_amdgcn_sched_barrier(0);
    f32x4 acc[2][3] = {};
    #pragma unroll
    for (int ks = 0; ks < 6; ++ks)
      #pragma unroll
      for (int m = 0; m < 2; ++m)
        #pragma unroll
        for (int g = 0; g < 3; ++g)
          acc[m][g] = __builtin_amdgcn_mfma_f32_16x16x32_f16(ah[m][ks], bw[g][ks], acc[m][g], 0, 0, 0);
    if (wave != 0) {
      #pragma unroll
      for (int m = 0; m < 2; ++m)
        #pragma unroll
        for (int g = 0; g < 3; ++g)
          *(f32x4*)&part[par][wave - 1][m][g][lane][0] = acc[m][g];
    }
    __syncthreads();                       // the ONE barrier per step
    if (wave == 0) {
      u16* hbn = hbuf + (size_t)((par ^ 1) * 2 + dir) * BATCH * HID;
      float outv[2][4];
      #pragma unroll
      for (int m = 0; m < 2; ++m) {
        f32x4 gh[3];
        #pragma unroll
        for (int g = 0; g < 3; ++g) {
          f32x4 v = acc[m][g];
          #pragma unroll
          for (int w = 0; w < 3; ++w) v += *(const f32x4*)&part[par][w][m][g][lane][0];
          gh[g] = v;
        }
        #pragma unroll
        for (int r = 0; r < 4; ++r) {
          int b = m * 16 + lk * 4 + r;
          float xr = h2f(g0[m][r]), xz = h2f(g1[m][r]), xn = h2f(g2[m][r]);
          float rg = 1.f / (1.f + __expf(-(xr + gh[0][r] + bh[0])));
          float zg = 1.f / (1.f + __expf(-(xz + gh[1][r] + bh[1])));
          float e2 = __expf(2.f * (xn + rg * (gh[2][r] + bh[2])));
          float ng = 1.f - 2.f / (e2 + 1.f);
          float hp = hst[m][r];
          bool msk = t < lenv[m][r];
          float hn = msk ? ((1.f - zg) * ng + zg * hp) : hp;
          hst[m][r] = hn;
          outv[m][r] = msk ? hn : 0.f;
          hx[b][lr] = f2h(hn);
        }
      }
      if (s + 1 < T_SEQ) {
        // transposed coherent publish of h_{s+1}, ack, flag
        asm volatile("s_waitcnt lgkmcnt(0)" ::: "memory");
        f16x8 hv = *(const f16x8*)&hx[lane >> 1][(lane & 1) * 8];
        store_coh16(&hbn[(size_t)(lane >> 1) * HID + hbase + (lane & 1) * 8], hv);
        wait_vm0();
        if (lane == 0)
          __hip_atomic_store(&flags[blk * FLAG_STRIDE], s + 2, __ATOMIC_RELAXED, __HIP_MEMORY_SCOPE_AGENT);
      }
      // tail (drained before next step's poll; other waves already pipelining)
      #pragma unroll
      for (int m = 0; m < 2; ++m)
        #pragma unroll
        for (int r = 0; r < 4; ++r) {
          int b = m * 16 + lk * 4 + r;
          __builtin_nontemporal_store(outv[m][r],
              &out[((size_t)t * BATCH + b) * (2 * HID) + (size_t)dir * HID + c]);
        }
      if (s + 1 < T_SEQ) {
        int t2 = dir ? (T_SEQ - 2 - s) : (s + 1);
        #pragma unroll
        for (int m = 0; m < 2; ++m)
          #pragma unroll
          for (int r = 0; r < 4; ++r) {
            int b = m * 16 + lk * 4 + r;
            size_t off = ((size_t)t2 * BATCH + b) * N_ALL + dir * G3 + c;
            g0[m][r] = gx[off]; g1[m][r] = gx[off + HID]; g2[m][r] = gx[off + 2 * HID];
          }
      }
      wait_vm0();
    }
  }
  if (wave == 0) {
    #pragma unroll
    for (int m = 0; m < 2; ++m)
      #pragma unroll
      for (int r = 0; r < 4; ++r) {
        int b = m * 16 + lk * 4 + r;
        out[(size_t)T_SEQ * BATCH * 2 * HID + (size_t)dir * BATCH * HID + (size_t)b * HID + c] = hst[m][r];
      }
  }
}

extern "C" void kernel_launch(void* const* d_in, const int* in_sizes, int n_in,
                              void* d_out, int out_size, void* d_ws, size_t ws_size,
                              hipStream_t stream) {
  const float* x     = (const float*)d_in[0];
  const float* h0    = (const float*)d_in[1];
  const float* wihf  = (const float*)d_in[2];
  const float* whhf  = (const float*)d_in[3];
  const float* bihf  = (const float*)d_in[4];
  const float* bhhf  = (const float*)d_in[5];
  const float* wihb  = (const float*)d_in[6];
  const float* whhb  = (const float*)d_in[7];
  const float* bihb  = (const float*)d_in[8];
  const float* bhhb  = (const float*)d_in[9];
  const int* lengths = (const int*)d_in[10];
  float* out = (float*)d_out;
  char* ws = (char*)d_ws;

  int* flags = (int*)(ws + 0);            //     12,288 B (96 slots x 128B)
  u16* whh_h = (u16*)(ws + 24576);        //  7,077,888 B
  u16* hbuf  = (u16*)(ws + 7102464);      //    196,608 B
  u16* gx    = (u16*)(ws + 7299072);      // 75,497,472 B

  k_cvt<<<1728, 256, 0, stream>>>(whhf, whh_h,            442368);
  k_cvt<<<1728, 256, 0, stream>>>(whhb, whh_h + 1769472,  442368);
  (void)hipMemsetAsync(flags, 0, NBLK * FLAG_STRIDE * sizeof(int), stream);
  k_gemm<<<dim3(36, 64), 256, 0, stream>>>(x, wihf, wihb, bihf, bihb, gx);
  k_gru<<<NBLK, 256, 0, stream>>>(whh_h, gx, h0, bhhf, bhhb, lengths, hbuf, out, flags);
}